// Round 3
// baseline (345.739 us; speedup 1.0000x reference)
//
#include <hip/hip_runtime.h>
#include <math.h>

namespace {

constexpr int B_  = 2;
constexpr int H_  = 96;
constexpr int W_  = 96;
constexpr int HW_ = H_ * W_;
constexpr int NC_ = 64;
constexpr int SC_ = 64;

// ---------------------------------------------------------------------------
// prep: transpose conv weights to wT[ic][tap][oc] (oc contiguous);
// pad w_off COUT 27->32; dcn weights k-major: wkT2[m'=k*64+ic][oc].
// ---------------------------------------------------------------------------
__global__ __launch_bounds__(256)
void prep_weights(const float* __restrict__ w1, const float* __restrict__ w2,
                  const float* __restrict__ woff, const float* __restrict__ wg,
                  const float* __restrict__ wbe, const float* __restrict__ wdcn,
                  float* __restrict__ w1T, float* __restrict__ w2T,
                  float* __restrict__ woffT, float* __restrict__ wgT,
                  float* __restrict__ wbeT, float* __restrict__ wkT2) {
    int idx = blockIdx.x * 256 + threadIdx.x;
    if (idx < 128 * 9 * 16) {   // w1: O=16, I=128
        int oc = idx % 16, rem = idx / 16, tap = rem % 9, ic = rem / 9;
        w1T[idx] = w1[(oc * 128 + ic) * 9 + tap];
    }
    if (idx < 16 * 9 * 64) {    // w2: O=64, I=16
        int oc = idx % 64, rem = idx / 64, tap = rem % 9, ic = rem / 9;
        w2T[idx] = w2[(oc * 16 + ic) * 9 + tap];
    }
    if (idx < 64 * 9 * 32) {    // w_off: O=27 (pad 32), I=64
        int oc = idx % 32, rem = idx / 32, tap = rem % 9, ic = rem / 9;
        woffT[idx] = (oc < 27) ? woff[(oc * 64 + ic) * 9 + tap] : 0.f;
    }
    if (idx < 64 * 9 * 64) {    // w_g / w_be: O=64, I=64 (tap-major per ic)
        int oc = idx % 64, rem = idx / 64, tap = rem % 9, ic = rem / 9;
        wgT[idx]  = wg [(oc * 64 + ic) * 9 + tap];
        wbeT[idx] = wbe[(oc * 64 + ic) * 9 + tap];
        // w_dcn k-major: m' = k*64 + ic
        int ic2 = rem % 64, k2 = rem / 64;
        wkT2[idx] = wdcn[(oc * 64 + ic2) * 9 + k2];
    }
}

// ---------------------------------------------------------------------------
// positional_norm: 288 blocks x 256 thr; block = 64 px, 4 ch-groups of 16
// ---------------------------------------------------------------------------
__global__ __launch_bounds__(256)
void norm_kernel(const float* __restrict__ x, float* __restrict__ nrm) {
    __shared__ float red1[4][64];
    __shared__ float red2[4][64];
    int blk = blockIdx.x;
    int b   = blk / 144;
    int p   = (blk % 144) * 64 + (threadIdx.x & 63);
    int cg  = threadIdx.x >> 6;

    float v[16];
    float s1 = 0.f, s2 = 0.f;
    const float* xb = x + ((size_t)b * NC_ + cg * 16) * HW_ + p;
    #pragma unroll
    for (int j = 0; j < 16; ++j) {
        v[j] = xb[j * HW_];
        s1 += v[j];
        s2 = fmaf(v[j], v[j], s2);
    }
    red1[cg][threadIdx.x & 63] = s1;
    red2[cg][threadIdx.x & 63] = s2;
    __syncthreads();
    int px = threadIdx.x & 63;
    s1 = red1[0][px] + red1[1][px] + red1[2][px] + red1[3][px];
    s2 = red2[0][px] + red2[1][px] + red2[2][px] + red2[3][px];
    float mean = s1 * (1.f / 64.f);
    float var  = (s2 - 64.f * mean * mean) * (1.f / 63.f);
    float inv  = 1.f / sqrtf(var + 1e-5f);
    float* nb = nrm + ((size_t)b * NC_ + cg * 16) * HW_ + p;
    #pragma unroll
    for (int j = 0; j < 16; ++j)
        nb[j * HW_] = (v[j] - mean) * inv;
}

// ---------------------------------------------------------------------------
// tiled implicit-GEMM 3x3 conv, pad 1. 256 threads, tile 16w x 4h = 64 px.
// Thread: OCB oc x 4 px (x2 if DUAL). pxg = t&15 (py=pxg>>2, px0=(pxg&3)*4),
// ocg = t>>4 (16 groups), oc0 = ocg*OCB. COUT/OCB must equal 16.
// ---------------------------------------------------------------------------
template <int CIN1, int CIN2, int COUT, int COUT_REAL, int OCB, int ICB,
          bool RELU, bool DUAL>
__global__ __launch_bounds__(256)
void conv_tiled(const float* __restrict__ in1, const float* __restrict__ in2,
                const float* __restrict__ wT, const float* __restrict__ wT2,
                const float* __restrict__ bias, const float* __restrict__ bias2,
                const float* __restrict__ nrm, float* __restrict__ out) {
    constexpr int CIN = CIN1 + CIN2;
    static_assert(COUT == OCB * 16, "need COUT/OCB == 16");
    constexpr int WSTRIDE = ICB * 9 * COUT;

    __shared__ float patch[ICB][6][20];
    __shared__ float wlds[(DUAL ? 2 : 1) * WSTRIDE];

    int t   = threadIdx.x;
    int blk = blockIdx.x;                 // 288 = B * 24 * 6
    int bx  = blk % 6;
    int by  = (blk / 6) % 24;
    int b   = blk / 144;
    int x0  = bx * 16, y0 = by * 4;

    int pxg = t & 15, ocg = t >> 4;
    int py  = pxg >> 2, px0 = (pxg & 3) * 4;
    int oc0 = ocg * OCB;

    float accA[OCB][4];
    float accB[DUAL ? OCB : 1][4];
    #pragma unroll
    for (int n = 0; n < OCB; ++n) {
        float bA = (oc0 + n < COUT_REAL) ? bias[oc0 + n] : 0.f;
        #pragma unroll
        for (int i = 0; i < 4; ++i) accA[n][i] = bA;
        if (DUAL) {
            float bB = (oc0 + n < COUT_REAL) ? bias2[oc0 + n] : 0.f;
            #pragma unroll
            for (int i = 0; i < 4; ++i) accB[n][i] = bB;
        }
    }

    for (int ic0 = 0; ic0 < CIN; ic0 += ICB) {
        // ---- stage input patch chunk ----
        for (int e = t; e < ICB * 108; e += 256) {
            int col = e % 18;
            int row = (e / 18) % 6;
            int ic  = e / 108;
            int yy = y0 + row - 1, xx = x0 + col - 1;
            float v = 0.f;
            if ((unsigned)yy < (unsigned)H_ && (unsigned)xx < (unsigned)W_) {
                int c = ic0 + ic;
                const float* src = (c < CIN1)
                    ? in1 + ((size_t)b * CIN1 + c) * HW_
                    : in2 + ((size_t)b * CIN2 + (c - CIN1)) * HW_;
                v = src[yy * W_ + xx];
            }
            patch[ic][row][col] = v;
        }
        // ---- stage weight chunk(s) ----
        {
            constexpr int W4 = WSTRIDE / 4;
            const float4* wsrc = (const float4*)(wT + (size_t)ic0 * 9 * COUT);
            float4* wdst = (float4*)&wlds[0];
            for (int j = t; j < W4; j += 256) wdst[j] = wsrc[j];
            if (DUAL) {
                const float4* ws2 = (const float4*)(wT2 + (size_t)ic0 * 9 * COUT);
                float4* wd2 = (float4*)&wlds[WSTRIDE];
                for (int j = t; j < W4; j += 256) wd2[j] = ws2[j];
            }
        }
        __syncthreads();

        // ---- accumulate ----
        for (int icc = 0; icc < ICB; ++icc) {
            float r[3][6];
            #pragma unroll
            for (int dy = 0; dy < 3; ++dy)
                #pragma unroll
                for (int j = 0; j < 6; ++j)
                    r[dy][j] = patch[icc][py + dy][px0 + j];

            #pragma unroll
            for (int tap = 0; tap < 9; ++tap) {
                constexpr int dyv[9] = {0,0,0,1,1,1,2,2,2};
                constexpr int dxv[9] = {0,1,2,0,1,2,0,1,2};
                int dy = dyv[tap], dx = dxv[tap];
                const float* wrow = &wlds[(icc * 9 + tap) * COUT + oc0];
                #pragma unroll
                for (int n = 0; n < OCB; ++n) {
                    float wv = wrow[n];
                    #pragma unroll
                    for (int i = 0; i < 4; ++i)
                        accA[n][i] = fmaf(wv, r[dy][dx + i], accA[n][i]);
                }
                if (DUAL) {
                    const float* wrow2 = &wlds[WSTRIDE + (icc * 9 + tap) * COUT + oc0];
                    #pragma unroll
                    for (int n = 0; n < OCB; ++n) {
                        float wv = wrow2[n];
                        #pragma unroll
                        for (int i = 0; i < 4; ++i)
                            accB[n][i] = fmaf(wv, r[dy][dx + i], accB[n][i]);
                    }
                }
            }
        }
        __syncthreads();
    }

    // ---- epilogue ----
    int xg = x0 + px0, yg = y0 + py;
    #pragma unroll
    for (int n = 0; n < OCB; ++n) {
        int oc = oc0 + n;
        if (oc >= COUT_REAL) continue;
        size_t off = ((size_t)b * COUT_REAL + oc) * HW_ + (size_t)yg * W_ + xg;
        float4 o4;
        if (DUAL) {
            const float4 nv = *reinterpret_cast<const float4*>(&nrm[off]);
            o4.x = fmaf(nv.x, 1.f + accA[n][0], accB[n][0]);
            o4.y = fmaf(nv.y, 1.f + accA[n][1], accB[n][1]);
            o4.z = fmaf(nv.z, 1.f + accA[n][2], accB[n][2]);
            o4.w = fmaf(nv.w, 1.f + accA[n][3], accB[n][3]);
        } else {
            o4.x = RELU ? fmaxf(accA[n][0], 0.f) : accA[n][0];
            o4.y = RELU ? fmaxf(accA[n][1], 0.f) : accA[n][1];
            o4.z = RELU ? fmaxf(accA[n][2], 0.f) : accA[n][2];
            o4.w = RELU ? fmaxf(accA[n][3], 0.f) : accA[n][3];
        }
        *reinterpret_cast<float4*>(&out[off]) = o4;
    }
}

// ---------------------------------------------------------------------------
// DCNv2 fused. Block = 16 pixels, 256 threads.
// phase0: 144 thr precompute mask-folded corner weights/indices -> LDS
// phase1: all thr gather: (pp = t>>4, sub = t&15), c = 4*sub+ci, float4 write
//         s[pp][k*64+c] (k-major; wkT2 matches)
// phase2: o = t&63, grp = t>>6 splits m' 4 ways; 16 px/thread; LDS reduce.
// ---------------------------------------------------------------------------
constexpr int SROW = 584;                 // 576 + 8, 16B-aligned rows

__global__ __launch_bounds__(256)
void dcn_kernel(const float* __restrict__ ref, const float* __restrict__ om,
                const float* __restrict__ wkT2, const float* __restrict__ b_dcn,
                float* __restrict__ out) {
    __shared__ float  smem[16 * SROW];    // s[pp][m'] ; reused as pr[64][65]
    __shared__ float4 cwL[144];
    __shared__ int4   ciL[144];

    int t  = threadIdx.x;
    int b  = blockIdx.x / 576;
    int p0 = (blockIdx.x % 576) * 16;

    const float* refb = ref + (size_t)b * SC_ * HW_;
    const float* omb  = om  + (size_t)b * 27  * HW_;

    // ---- phase 0 ----
    if (t < 144) {
        int pp = t / 9, k = t % 9;
        int p  = p0 + pp;
        int y  = p / W_, x = p % W_;
        float dy = omb[(2 * k)     * HW_ + p];
        float dx = omb[(2 * k + 1) * HW_ + p];
        float mk = omb[(18 + k)    * HW_ + p];
        mk = 1.f / (1.f + expf(-mk));

        float py = dy + (float)y + (float)(k / 3 - 1);
        float px = dx + (float)x + (float)(k % 3 - 1);
        float fy = floorf(py), fx = floorf(px);
        int   y0 = (int)fy,   x0 = (int)fx;
        float wy = py - fy,   wx = px - fx;

        float cw[4];
        int   ci[4];
        #pragma unroll
        for (int i = 0; i < 4; ++i) {
            int yy = y0 + (i >> 1);
            int xx = x0 + (i & 1);
            bool valid = (yy >= 0) && (yy < H_) && (xx >= 0) && (xx < W_);
            int yc = yy < 0 ? 0 : (yy > H_ - 1 ? H_ - 1 : yy);
            int xc = xx < 0 ? 0 : (xx > W_ - 1 ? W_ - 1 : xx);
            ci[i] = yc * W_ + xc;
            float wyi = (i >> 1) ? wy : (1.f - wy);
            float wxi = (i & 1)  ? wx : (1.f - wx);
            cw[i] = valid ? mk * wyi * wxi : 0.f;
        }
        cwL[t] = make_float4(cw[0], cw[1], cw[2], cw[3]);
        ciL[t] = make_int4(ci[0], ci[1], ci[2], ci[3]);
    }
    __syncthreads();

    // ---- phase 1: gather ----
    {
        int pp = t >> 4, sub = t & 15;
        #pragma unroll
        for (int k = 0; k < 9; ++k) {
            float4 cw = cwL[pp * 9 + k];
            int4   ci = ciL[pp * 9 + k];
            float sv[4];
            #pragma unroll
            for (int j = 0; j < 4; ++j) {
                const float* rc = refb + (size_t)(sub * 4 + j) * HW_;
                sv[j] = cw.x * rc[ci.x] + cw.y * rc[ci.y]
                      + cw.z * rc[ci.z] + cw.w * rc[ci.w];
            }
            *reinterpret_cast<float4*>(&smem[pp * SROW + k * 64 + sub * 4]) =
                make_float4(sv[0], sv[1], sv[2], sv[3]);
        }
    }
    __syncthreads();

    // ---- phase 2: matvec, m' split across 4 waves ----
    int o = t & 63, grp = t >> 6;
    float acc[16];
    #pragma unroll
    for (int i = 0; i < 16; ++i) acc[i] = 0.f;

    int m0 = grp * 144;
    for (int m4 = m0; m4 < m0 + 144; m4 += 4) {
        float w0 = wkT2[(size_t)(m4 + 0) * 64 + o];
        float w1 = wkT2[(size_t)(m4 + 1) * 64 + o];
        float w2 = wkT2[(size_t)(m4 + 2) * 64 + o];
        float w3 = wkT2[(size_t)(m4 + 3) * 64 + o];
        #pragma unroll
        for (int pp = 0; pp < 16; ++pp) {
            const float4 sv = *reinterpret_cast<const float4*>(&smem[pp * SROW + m4]);
            acc[pp] = fmaf(w0, sv.x, acc[pp]);
            acc[pp] = fmaf(w1, sv.y, acc[pp]);
            acc[pp] = fmaf(w2, sv.z, acc[pp]);
            acc[pp] = fmaf(w3, sv.w, acc[pp]);
        }
    }
    __syncthreads();

    // ---- partials into LDS (aliased over s) ----
    float* pr = smem;                     // pr[(g*16+pp)*65 + o]
    #pragma unroll
    for (int pp = 0; pp < 16; ++pp)
        pr[(grp * 16 + pp) * 65 + o] = acc[pp];
    __syncthreads();

    // ---- reduce & store (coalesced over pp) ----
    {
        int pp = t & 15, ob = t >> 4;     // ob 0..15
        float* outb = out + (size_t)b * SC_ * HW_;
        #pragma unroll
        for (int rep = 0; rep < 4; ++rep) {
            int oo = ob + rep * 16;
            float v = pr[(0 * 16 + pp) * 65 + oo]
                    + pr[(1 * 16 + pp) * 65 + oo]
                    + pr[(2 * 16 + pp) * 65 + oo]
                    + pr[(3 * 16 + pp) * 65 + oo]
                    + b_dcn[oo];
            outb[(size_t)oo * HW_ + p0 + pp] = v;
        }
    }
}

} // namespace

// ---------------------------------------------------------------------------
extern "C" void kernel_launch(void* const* d_in, const int* in_sizes, int n_in,
                              void* d_out, int out_size, void* d_ws, size_t ws_size,
                              hipStream_t stream) {
    (void)in_sizes; (void)n_in; (void)out_size; (void)ws_size;

    const float* x     = (const float*)d_in[0];
    const float* ref   = (const float*)d_in[1];
    const float* w1    = (const float*)d_in[2];
    const float* b1    = (const float*)d_in[3];
    const float* w2    = (const float*)d_in[4];
    const float* b2    = (const float*)d_in[5];
    const float* w_off = (const float*)d_in[6];
    const float* b_off = (const float*)d_in[7];
    const float* w_dcn = (const float*)d_in[8];
    const float* b_dcn = (const float*)d_in[9];
    const float* w_g   = (const float*)d_in[10];
    const float* b_g   = (const float*)d_in[11];
    const float* w_be  = (const float*)d_in[12];
    const float* b_be  = (const float*)d_in[13];

    float* out = (float*)d_out;
    float* ws  = (float*)d_ws;

    float* nrm   = ws;                      // 1,179,648
    float* hmid  = nrm   + 1179648;         //   294,912
    float* cond  = hmid  + 294912;          // 1,179,648
    float* om    = cond  + 1179648;         //   497,664
    float* rr    = om    + 497664;          // 1,179,648
    float* w1T   = rr    + 1179648;         //    18,432
    float* w2T   = w1T   + 18432;           //     9,216
    float* woffT = w2T   + 9216;            //    18,432
    float* wgT   = woffT + 18432;           //    36,864
    float* wbeT  = wgT   + 36864;           //    36,864
    float* wkT2  = wbeT  + 36864;           //    36,864

    prep_weights<<<144, 256, 0, stream>>>(w1, w2, w_off, w_g, w_be, w_dcn,
                                          w1T, w2T, woffT, wgT, wbeT, wkT2);

    norm_kernel<<<288, 256, 0, stream>>>(x, nrm);

    constexpr int GRID = 288;

    // conv1: 128 -> 16, ReLU. OCB=1.
    conv_tiled<64, 64, 16, 16, 1, 16, true, false>
        <<<GRID, 256, 0, stream>>>(nrm, ref, w1T, nullptr, b1, nullptr, nullptr, hmid);

    // conv2: 16 -> 64, ReLU. OCB=4.
    conv_tiled<16, 0, 64, 64, 4, 16, true, false>
        <<<GRID, 256, 0, stream>>>(hmid, nullptr, w2T, nullptr, b2, nullptr, nullptr, cond);

    // conv_off: 64 -> 27 (pad 32). OCB=2.
    conv_tiled<64, 0, 32, 27, 2, 8, false, false>
        <<<GRID, 256, 0, stream>>>(cond, nullptr, woffT, nullptr, b_off, nullptr, nullptr, om);

    dcn_kernel<<<B_ * 576, 256, 0, stream>>>(ref, om, wkT2, b_dcn, rr);

    // final: gamma/beta DUAL + fused affine epilogue. OCB=4.
    conv_tiled<64, 0, 64, 64, 4, 8, false, true>
        <<<GRID, 256, 0, stream>>>(rr, nullptr, wgT, wbeT, b_g, b_be, nrm, out);
}